// Round 6
// baseline (1842.004 us; speedup 1.0000x reference)
//
#include <hip/hip_runtime.h>
#include <hip/hip_bf16.h>
#include <stdint.h>

#define BB 256
#define CC 1024
#define NP 25
#define EPS 1e-5f

typedef __attribute__((ext_vector_type(8))) short bf16x8;
typedef __attribute__((ext_vector_type(4))) float f32x4;
typedef __attribute__((ext_vector_type(16))) float f32x16;
typedef unsigned int u32;

#define MFMA32(A, B, C) __builtin_amdgcn_mfma_f32_32x32x16_bf16(A, B, C, 0, 0, 0)

// async global->LDS, 16B per lane; LDS dest = wave-uniform base + lane*16
__device__ __forceinline__ void gload16(const u32* g, u32* l)
{
  __builtin_amdgcn_global_load_lds(
      (const __attribute__((address_space(1))) u32*)g,
      (__attribute__((address_space(3))) u32*)l, 16, 0, 0);
}

// ---------------------------------------------------------------- utils

__device__ __forceinline__ void head_entry(int j, int* pp, int* ww)
{
  int cnt = 0;
  for (int y1 = 0; y1 < 5; y1++)
    for (int x1 = 0; x1 < 5; x1++) {
      int p = y1 * 5 + x1;
      int y2 = y1 + 2, x2 = x1 + 2;
      if (y2 == 2 || y2 == 3)
        for (int s = 0; s < 3; s++) { if (y2 + s + 1 > 6) break; if (cnt == j) { *pp = p; *ww = 0 + s; return; } cnt++; }
      if (y1 == 3 || y1 == 4)
        for (int s = 0; s < 3; s++) { if (y1 - (s + 1) < 0) break; if (cnt == j) { *pp = p; *ww = 3 + s; return; } cnt++; }
      if (x2 == 2 || x2 == 3)
        for (int s = 0; s < 3; s++) { if (x2 + s + 1 > 6) break; if (cnt == j) { *pp = p; *ww = 6 + s; return; } cnt++; }
      if (x1 == 3 || x1 == 4)
        for (int s = 0; s < 3; s++) { if (x1 - (s + 1) < 0) break; if (cnt == j) { *pp = p; *ww = 9 + s; return; } cnt++; }
    }
}

// split fp32 -> hi bf16 (truncate) + lo bf16 (remainder); pack pairs into u32
__device__ __forceinline__ void split_f4(float4 f, uint2& h, uint2& l)
{
  u32 ux = __float_as_uint(f.x), uy = __float_as_uint(f.y);
  u32 uz = __float_as_uint(f.z), uw = __float_as_uint(f.w);
  h.x = (ux >> 16) | (uy & 0xFFFF0000u);
  h.y = (uz >> 16) | (uw & 0xFFFF0000u);
  float lx = f.x - __uint_as_float(ux & 0xFFFF0000u);
  float ly = f.y - __uint_as_float(uy & 0xFFFF0000u);
  float lz = f.z - __uint_as_float(uz & 0xFFFF0000u);
  float lw = f.w - __uint_as_float(uw & 0xFFFF0000u);
  l.x = (__float_as_uint(lx) >> 16) | (__float_as_uint(ly) & 0xFFFF0000u);
  l.y = (__float_as_uint(lz) >> 16) | (__float_as_uint(lw) & 0xFFFF0000u);
}

// ------------------------------------------------- layer-1 stats from x

__global__ void k_xsums(const float* __restrict__ x, float* __restrict__ xs1,
                        float* __restrict__ xs2)
{
  int pos = blockIdx.x * 256 + threadIdx.x;   // < 50176
  float s1 = 0.f, s2 = 0.f;
  for (int b = 0; b < BB; b++) {
    float v = x[(size_t)b * 50176 + pos];
    s1 += v; s2 = fmaf(v, v, s2);
  }
  xs1[pos] = s1; xs2[pos] = s2;
}

__global__ void k_stats1(const float* __restrict__ xs1, const float* __restrict__ xs2,
                         const float* __restrict__ gam, const float* __restrict__ bet,
                         float* __restrict__ ssc, float* __restrict__ ssh)
{
  int p = blockIdx.x;
  int c = blockIdx.y * 256 + threadIdx.x;
  int y1 = p / 5, x1 = p % 5;
  float s1 = 0.f, s2 = 0.f;
  for (int dy = 0; dy < 3; dy++)
    for (int dx = 0; dx < 3; dx++) {
      int pos = c * 49 + (y1 + dy) * 7 + (x1 + dx);
      s1 += xs1[pos]; s2 += xs2[pos];
    }
  const float inv = 1.0f / 2304.0f;
  float mean = s1 * inv;
  float var  = s2 * inv - mean * mean;
  float rs   = rsqrtf(var + EPS);
  float sc   = rs * gam[c];
  ssc[(size_t)p * CC + c] = sc;
  ssh[(size_t)p * CC + c] = bet[c] - mean * sc;
}

// ------------------------- one-time x transpose: x[b][c][yx] -> xt[b][yx][c]

__global__ void k_transpose(const float* __restrict__ x, float* __restrict__ xt)
{
  __shared__ float tile[128][51];
  int b = blockIdx.x, cg = blockIdx.y;
  const float* src = x + (size_t)b * 50176 + (size_t)cg * 128 * 49;
  for (int idx = threadIdx.x; idx < 6272; idx += 256)
    tile[idx / 49][idx % 49] = src[idx];
  __syncthreads();
  float* dst = xt + (size_t)b * 49 * 1024 + cg * 128;
  for (int pp = 0; pp < 50; pp += 2) {
    int p = pp + (threadIdx.x >> 7);
    int i = threadIdx.x & 127;
    if (p < 49) dst[(size_t)p * 1024 + i] = tile[i][p];
  }
}

// -------------- fallback patch gather + BN1 affine + relu (small-ws tier)

__global__ void k_gather(const float* __restrict__ x, const float* __restrict__ ssc,
                         const float* __restrict__ ssh, float* __restrict__ out,
                         int pbase)
{
  int tid = threadIdx.x;
  int r0 = blockIdx.x * 16;
  for (int rr = 0; rr < 16; rr++) {
    int row = r0 + rr;
    int pl = row / 2304;
    int b  = (row / 9) & 255;
    int yx = row % 9;
    int pg = pbase + pl;
    int pos = (pg / 5 + yx / 3) * 7 + (pg % 5) + (yx % 3);
    const float* xb  = x + (size_t)b * CC * 49 + pos;
    const float* scp = ssc + (size_t)pg * CC;
    const float* shp = ssh + (size_t)pg * CC;
    float* op = out + (size_t)row * CC;
    #pragma unroll
    for (int q = 0; q < 4; q++) {
      int c = q * 256 + tid;
      float v = xb[(size_t)c * 49];
      op[c] = fmaxf(fmaf(v, scp[c], shp[c]), 0.f);
    }
  }
}

// ---------- weight/ctx pre-split into gload-ready interleaved hi/lo layout
// out row = 1024 u32: [slab 0..31][ 16 u32 hi pairs | 16 u32 lo pairs ]

__global__ void k_wsplit(const float* __restrict__ w, u32* __restrict__ dst, int total)
{
  int g = blockIdx.x * 256 + threadIdx.x;
  if (g >= total) return;
  int row = g >> 10;
  int rem = g & 1023;
  int slab = rem >> 5, j = rem & 31;
  int lo = j >> 4, jj = j & 15;
  const float* src = w + ((size_t)row << 10) + slab * 32 + 2 * jj;
  float f0 = src[0], f1 = src[1];
  u32 u0 = __float_as_uint(f0), u1 = __float_as_uint(f1);
  u32 v;
  if (lo == 0) {
    v = (u0 >> 16) | (u1 & 0xFFFF0000u);
  } else {
    float l0 = f0 - __uint_as_float(u0 & 0xFFFF0000u);
    float l1 = f1 - __uint_as_float(u1 & 0xFFFF0000u);
    v = (__float_as_uint(l0) >> 16) | (__float_as_uint(l1) & 0xFFFF0000u);
  }
  dst[g] = v;
}

// ------------------------------- BN3 affine + relu + 3x3 mean (vectorized)

__global__ void k_pool(const float* __restrict__ h, const float* __restrict__ ssc,
                       const float* __restrict__ ssh, float* __restrict__ apool,
                       int pbase)
{
  int row = blockIdx.x;                 // pl*256 + b
  int pl = row >> 8;
  int pg = pbase + pl;
  int c = threadIdx.x * 4;
  float4 sc = *(const float4*)(ssc + (size_t)pg * CC + c);
  float4 sh = *(const float4*)(ssh + (size_t)pg * CC + c);
  const float* hp = h + (size_t)row * 9 * CC + c;
  float4 s = {0.f, 0.f, 0.f, 0.f};
  #pragma unroll
  for (int yx = 0; yx < 9; yx++) {
    float4 v = *(const float4*)(hp + (size_t)yx * CC);
    s.x += fmaxf(fmaf(v.x, sc.x, sh.x), 0.f);
    s.y += fmaxf(fmaf(v.y, sc.y, sh.y), 0.f);
    s.z += fmaxf(fmaf(v.z, sc.z, sh.z), 0.f);
    s.w += fmaxf(fmaf(v.w, sc.w, sh.w), 0.f);
  }
  const float inv = 1.0f / 9.0f;
  float4 o = { s.x * inv, s.y * inv, s.z * inv, s.w * inv };
  *(float4*)(apool + (size_t)row * CC + c) = o;
}

// ------------------- finalize BN stats from per-mblock partials (18/patch)

__global__ void k_statsfin(const float* __restrict__ part, const float* __restrict__ gam,
                           const float* __restrict__ bet, float* __restrict__ ssc,
                           float* __restrict__ ssh, int pbase)
{
  int pl = blockIdx.x;
  int c  = blockIdx.y * 256 + threadIdx.x;
  float s1 = 0.f, s2 = 0.f;
  for (int mb = 0; mb < 18; mb++) {
    const float* pp = part + ((size_t)(pl * 18 + mb) * CC + c) * 2;
    s1 += pp[0]; s2 += pp[1];
  }
  const float inv = 1.0f / 2304.0f;
  float mean = s1 * inv;
  float var  = s2 * inv - mean * mean;
  float rs   = rsqrtf(var + EPS);
  float sc   = rs * gam[c];
  int pg = pbase + pl;
  ssc[(size_t)pg * CC + c] = sc;
  ssh[(size_t)pg * CC + c] = bet[c] - mean * sc;
}

// ------------------------------------------------------------ MFMA GEMM core
// C[m][n] = sum_k f(A[m][k]) * B[n][k] + bias[n]
// split-bf16 via 32x32x16 MFMA: acc += ah*bh + al*bh + ah*bl (fp32 acc)
// LDS layout per 128-row tile: row*32 u32; granule g (16B) at phys g^(row&7);
//   hi plane granules 0..3 (k 0..31), lo plane granules 4..7.
// MODE: 0 = A fp32 reg-staged; 1 = +BN affine/relu; 2 = +xt row-map (conv1);
//       3 = A pre-split, gload (heads). B always pre-split via global_load_lds.
// STATS: emit per-block column sum/sumsq to part[mb][col][2].

template<int MODE, bool STATS>
__device__ __forceinline__ void mg_body(
    const float* __restrict__ Af, const u32* __restrict__ Agl,
    const u32* __restrict__ Bp, const float* __restrict__ bias,
    float* __restrict__ Cmat, const float* __restrict__ ssc,
    const float* __restrict__ ssh, int pbase, int m0, int n0,
    float* __restrict__ part, int mb)
{
  __shared__ u32 sA[2][4096];
  __shared__ u32 sB[2][4096];
  __shared__ float sr1[4][64];
  __shared__ float sr2[4][64];

  const int t = threadIdx.x;
  const int l = t & 63, wv = t >> 6;
  const int l31 = l & 31, l5 = l >> 5;
  const int wm = (wv >> 1) * 64, wn = (wv & 1) * 64;

  // fragment read offsets (u32), granule XOR swizzle.
  // 32x32x16 A/B input layout: row = lane&31, k = (lane>>5)*8 + j.
  // granule = (l>>5) + 2*kh (+4 for lo plane).
  int fA[2][2][2], fB[2][2][2];    // [rb|cb][kh][plane]
  #pragma unroll
  for (int rb = 0; rb < 2; rb++) {
    int Ra = wm + rb * 32 + l31;
    int Rb = wn + rb * 32 + l31;
    #pragma unroll
    for (int kh = 0; kh < 2; kh++) {
      #pragma unroll
      for (int pl_ = 0; pl_ < 2; pl_++) {
        int g = l5 + 2 * kh + 4 * pl_;
        fA[rb][kh][pl_] = Ra * 32 + ((g ^ (Ra & 7)) << 2);
        fB[rb][kh][pl_] = Rb * 32 + ((g ^ (Rb & 7)) << 2);
      }
    }
  }

  // gload addressing: wave covers rows wv*32..wv*32+31 in 4 chunks of 8 rows
  int growq[4], ggq[4];
  #pragma unroll
  for (int q = 0; q < 4; q++) {
    int rr = wv * 32 + q * 8 + (l >> 3);
    growq[q] = rr;
    ggq[q] = (((l & 7) ^ (rr & 7)) << 2);
  }
  const u32* Brow = Bp + (size_t)n0 * 1024;
  const u32* Agr  = (MODE == 3) ? (Agl + (size_t)m0 * 1024) : nullptr;

  // reg-staging setup (MODE<3): thread = (row sr, 16-float half sh_)
  const int sr = t >> 1, sh_ = t & 1;
  const float *arow = nullptr, *scp = nullptr, *shp = nullptr;
  int wA[4] = {0, 0, 0, 0};
  if (MODE < 3) {
    wA[0] = sr * 32 + (((2 * sh_)     ^ (sr & 7)) << 2);
    wA[1] = sr * 32 + (((2 * sh_ + 1) ^ (sr & 7)) << 2);
    wA[2] = sr * 32 + (((4 + 2 * sh_) ^ (sr & 7)) << 2);
    wA[3] = sr * 32 + (((5 + 2 * sh_) ^ (sr & 7)) << 2);
    if (MODE == 2) {
      int pl = m0 / 2304, pg = pbase + pl;
      int q = m0 + sr - pl * 2304;
      int b = q / 9, yx = q % 9;
      int pos = (pg / 5 + yx / 3) * 7 + (pg % 5) + (yx % 3);
      arow = Af + ((size_t)b * 49 + pos) * CC + sh_ * 16;
      scp = ssc + (size_t)pg * CC + sh_ * 16;
      shp = ssh + (size_t)pg * CC + sh_ * 16;
    } else {
      arow = Af + (size_t)(m0 + sr) * CC + sh_ * 16;
      if (MODE == 1) {
        int pl = m0 / 2304, pg = pbase + pl;
        scp = ssc + (size_t)pg * CC + sh_ * 16;
        shp = ssh + (size_t)pg * CC + sh_ * 16;
      }
    }
  }

  f32x16 acc[2][2];
  #pragma unroll
  for (int i = 0; i < 2; i++)
    #pragma unroll
    for (int j = 0; j < 2; j++)
      #pragma unroll
      for (int e = 0; e < 16; e++) acc[i][j][e] = 0.f;

  float4 areg[4];

  // prologue: stage slab 0
  {
    #pragma unroll
    for (int q = 0; q < 4; q++)
      gload16(Brow + (size_t)growq[q] * 1024 + ggq[q],
              &sB[0][(wv * 32 + q * 8) * 32]);
    if (MODE == 3) {
      #pragma unroll
      for (int q = 0; q < 4; q++)
        gload16(Agr + (size_t)growq[q] * 1024 + ggq[q],
                &sA[0][(wv * 32 + q * 8) * 32]);
    } else {
      areg[0] = *(const float4*)(arow + 0);
      areg[1] = *(const float4*)(arow + 4);
      areg[2] = *(const float4*)(arow + 8);
      areg[3] = *(const float4*)(arow + 12);
      if (MODE == 1 || MODE == 2) {
        #pragma unroll
        for (int v = 0; v < 4; v++) {
          float4 s = *(const float4*)(scp + v * 4);
          float4 h = *(const float4*)(shp + v * 4);
          areg[v].x = fmaxf(fmaf(areg[v].x, s.x, h.x), 0.f);
          areg[v].y = fmaxf(fmaf(areg[v].y, s.y, h.y), 0.f);
          areg[v].z = fmaxf(fmaf(areg[v].z, s.z, h.z), 0.f);
          areg[v].w = fmaxf(fmaf(areg[v].w, s.w, h.w), 0.f);
        }
      }
      uint2 h0, l0, h1, l1, h2, l2, h3, l3;
      split_f4(areg[0], h0, l0); split_f4(areg[1], h1, l1);
      split_f4(areg[2], h2, l2); split_f4(areg[3], h3, l3);
      *(uint4*)&sA[0][wA[0]] = make_uint4(h0.x, h0.y, h1.x, h1.y);
      *(uint4*)&sA[0][wA[1]] = make_uint4(h2.x, h2.y, h3.x, h3.y);
      *(uint4*)&sA[0][wA[2]] = make_uint4(l0.x, l0.y, l1.x, l1.y);
      *(uint4*)&sA[0][wA[3]] = make_uint4(l2.x, l2.y, l3.x, l3.y);
    }
  }
  __syncthreads();

  #pragma unroll 1
  for (int it = 0; it < 32; ++it) {
    const int cur = it & 1, nxt = cur ^ 1;
    const int kk2 = (it + 1) << 5;
    const bool pf = (it < 31);
    if (pf) {
      int so = kk2;                    // u32 offset of next 32-k slab
      #pragma unroll
      for (int q = 0; q < 4; q++)
        gload16(Brow + (size_t)growq[q] * 1024 + so + ggq[q],
                &sB[nxt][(wv * 32 + q * 8) * 32]);
      if (MODE == 3) {
        #pragma unroll
        for (int q = 0; q < 4; q++)
          gload16(Agr + (size_t)growq[q] * 1024 + so + ggq[q],
                  &sA[nxt][(wv * 32 + q * 8) * 32]);
      } else {
        areg[0] = *(const float4*)(arow + kk2);
        areg[1] = *(const float4*)(arow + kk2 + 4);
        areg[2] = *(const float4*)(arow + kk2 + 8);
        areg[3] = *(const float4*)(arow + kk2 + 12);
      }
    }
    // compute on cur
    bf16x8 Ah[2][2], Al_[2][2], Bh[2][2], Bl[2][2];   // [rb|cb][kh]
    #pragma unroll
    for (int rb = 0; rb < 2; rb++)
      #pragma unroll
      for (int kh = 0; kh < 2; kh++) {
        Ah[rb][kh]  = *(const bf16x8*)&sA[cur][fA[rb][kh][0]];
        Al_[rb][kh] = *(const bf16x8*)&sA[cur][fA[rb][kh][1]];
        Bh[rb][kh]  = *(const bf16x8*)&sB[cur][fB[rb][kh][0]];
        Bl[rb][kh]  = *(const bf16x8*)&sB[cur][fB[rb][kh][1]];
      }
    #pragma unroll
    for (int rb = 0; rb < 2; rb++)
      #pragma unroll
      for (int cb = 0; cb < 2; cb++)
        #pragma unroll
        for (int kh = 0; kh < 2; kh++) {
          acc[rb][cb] = MFMA32(Ah[rb][kh],  Bh[cb][kh], acc[rb][cb]);
          acc[rb][cb] = MFMA32(Al_[rb][kh], Bh[cb][kh], acc[rb][cb]);
          acc[rb][cb] = MFMA32(Ah[rb][kh],  Bl[cb][kh], acc[rb][cb]);
        }
    if (pf && MODE < 3) {
      if (MODE == 1 || MODE == 2) {
        #pragma unroll
        for (int v = 0; v < 4; v++) {
          float4 s = *(const float4*)(scp + kk2 + v * 4);
          float4 h = *(const float4*)(shp + kk2 + v * 4);
          areg[v].x = fmaxf(fmaf(areg[v].x, s.x, h.x), 0.f);
          areg[v].y = fmaxf(fmaf(areg[v].y, s.y, h.y), 0.f);
          areg[v].z = fmaxf(fmaf(areg[v].z, s.z, h.z), 0.f);
          areg[v].w = fmaxf(fmaf(areg[v].w, s.w, h.w), 0.f);
        }
      }
      uint2 h0, l0, h1, l1, h2, l2, h3, l3;
      split_f4(areg[0], h0, l0); split_f4(areg[1], h1, l1);
      split_f4(areg[2], h2, l2); split_f4(areg[3], h3, l3);
      *(uint4*)&sA[nxt][wA[0]] = make_uint4(h0.x, h0.y, h1.x, h1.y);
      *(uint4*)&sA[nxt][wA[1]] = make_uint4(h2.x, h2.y, h3.x, h3.y);
      *(uint4*)&sA[nxt][wA[2]] = make_uint4(l0.x, l0.y, l1.x, l1.y);
      *(uint4*)&sA[nxt][wA[3]] = make_uint4(l2.x, l2.y, l3.x, l3.y);
    }
    __syncthreads();
  }

  // epilogue: 32x32 D layout [m74/m101]: col = lane&31,
  // row = (reg&3) + 8*(reg>>2) + 4*(lane>>5); optional column stats.
  float st1[2], st2[2];
  st1[0] = st1[1] = st2[0] = st2[1] = 0.f;
  #pragma unroll
  for (int cb = 0; cb < 2; cb++) {
    int ocol = n0 + wn + cb * 32 + l31;
    float bj = bias[ocol];
    #pragma unroll
    for (int rb = 0; rb < 2; rb++) {
      int rbase = m0 + wm + rb * 32 + 4 * l5;
      #pragma unroll
      for (int reg = 0; reg < 16; reg++) {
        int orow = rbase + (reg & 3) + 8 * (reg >> 2);
        float v = acc[rb][cb][reg] + bj;
        Cmat[(size_t)orow * CC + ocol] = v;
        if (STATS) { st1[cb] += v; st2[cb] = fmaf(v, v, st2[cb]); }
      }
    }
  }
  if (STATS) {
    #pragma unroll
    for (int cb = 0; cb < 2; cb++) {
      st1[cb] += __shfl_xor(st1[cb], 32, 64);
      st2[cb] += __shfl_xor(st2[cb], 32, 64);
    }
    if (l < 32) {
      sr1[wv][l]      = st1[0];
      sr1[wv][32 + l] = st1[1];
      sr2[wv][l]      = st2[0];
      sr2[wv][32 + l] = st2[1];
    }
    __syncthreads();
    if (t < 128) {
      int ch = t >> 6, c6 = t & 63;
      float a1 = sr1[ch][c6] + sr1[ch + 2][c6];
      float a2 = sr2[ch][c6] + sr2[ch + 2][c6];
      float2 o = { a1, a2 };
      *(float2*)(part + ((size_t)mb * CC + n0 + t) * 2) = o;
    }
  }
}

template<int MODE, bool STATS>
__global__ __launch_bounds__(256, 2)
void k_mg(const float* __restrict__ Af, const u32* __restrict__ Bp,
          const float* __restrict__ bias, float* __restrict__ Cmat,
          const float* __restrict__ ssc, const float* __restrict__ ssh,
          int pbase, float* __restrict__ part)
{
  mg_body<MODE, STATS>(Af, nullptr, Bp, bias, Cmat, ssc, ssh, pbase,
                       blockIdx.x * 128, blockIdx.y * 128, part, blockIdx.x);
}

template<int MODE>
__global__ __launch_bounds__(256, 2)
void k_heads(const float* __restrict__ ctx, const u32* __restrict__ ctxp,
             const u32* __restrict__ wplh, const float* __restrict__ lb,
             float* __restrict__ out)
{
  int p, w;
  head_entry(blockIdx.y, &p, &w);
  mg_body<MODE, false>(ctx + (size_t)p * BB * CC,
                       ctxp ? ctxp + (size_t)p * BB * 1024 : nullptr,
                       wplh + (size_t)w * 1048576,
                       lb + (size_t)w * CC,
                       out + (size_t)blockIdx.y * BB * CC,
                       nullptr, nullptr, 0,
                       (blockIdx.x >> 3) * 128, (blockIdx.x & 7) * 128,
                       nullptr, 0);
}

// ---------------------------------------------------------------- launch

extern "C" void kernel_launch(void* const* d_in, const int* in_sizes, int n_in,
                              void* d_out, int out_size, void* d_ws, size_t ws_size,
                              hipStream_t stream)
{
  const float* x   = (const float*)d_in[0];
  const float* bng = (const float*)d_in[1];
  const float* bnb = (const float*)d_in[2];
  const float* cw  = (const float*)d_in[3];
  const float* cb  = (const float*)d_in[4];
  const float* lw  = (const float*)d_in[5];
  const float* lb  = (const float*)d_in[6];
  float* out = (float*)d_out;
  float* ws  = (float*)d_ws;

  const size_t W = ws_size / 4;           // 4-byte words
  const size_t SZ_WPL = 15ull * 1048576;
  const size_t SZ_XT  = 256ull * 49 * 1024;
  const size_t SZ_G   = 2304ull * 1024;
  const size_t SZ_CTX = 6400ull * 1024;
  const size_t SZ_XS  = 50176;
  const size_t SZ_SS  = 25ull * 1024;

  auto need = [&](int PC, bool xt, bool cp) -> size_t {
    size_t Mc = (size_t)PC * 2304;
    return SZ_WPL + (xt ? SZ_XT : SZ_G) + 2 * Mc * 1024
         + (size_t)PC * 256 * 1024 + SZ_CTX + 2 * SZ_XS + 2 * SZ_SS
         + (Mc / 128) * 1024 * 2 + (cp ? SZ_CTX : 0);
  };
  int PC; bool useXT, useCP;
  if      (W >= need(25, true, true)) { PC = 25; useXT = true;  useCP = true;  }
  else if (W >= need(5, true, true))  { PC = 5;  useXT = true;  useCP = true;  }
  else if (W >= need(5, true, false)) { PC = 5;  useXT = true;  useCP = false; }
  else if (W >= need(1, true, false)) { PC = 1;  useXT = true;  useCP = false; }
  else                                { PC = 1;  useXT = false; useCP = false; }

  const int NCH = NP / PC;
  const size_t Mc = (size_t)PC * 2304;

  u32*   wpl    = (u32*)ws;
  float* xtg    = (float*)(wpl + SZ_WPL);       // xt (or gather buf in low tier)
  float* h1     = xtg + (useXT ? SZ_XT : SZ_G);
  float* h2     = h1 + Mc * 1024;
  float* pooled = h2 + Mc * 1024;
  float* ctx    = pooled + (size_t)PC * 256 * 1024;
  float* xs1    = ctx + SZ_CTX;
  float* xs2    = xs1 + SZ_XS;
  float* ssc    = xs2 + SZ_XS;
  float* ssh    = ssc + SZ_SS;
  float* part   = ssh + SZ_SS;
  u32*   ctxp   = (u32*)(part + (Mc / 128) * 1024 * 2);

  // pre-split all 15 weight matrices into gload layout
  k_wsplit<<<(3 * 1048576) / 256, 256, 0, stream>>>(cw, wpl, 3 * 1048576);
  k_wsplit<<<(12 * 1048576) / 256, 256, 0, stream>>>(lw, wpl + 3ull * 1048576,
                                                     12 * 1048576);
  if (useXT) k_transpose<<<dim3(256, 8), 256, 0, stream>>>(x, xtg);
  k_xsums<<<196, 256, 0, stream>>>(x, xs1, xs2);
  k_stats1<<<dim3(25, 4), 256, 0, stream>>>(xs1, xs2, bng, bnb, ssc, ssh);

  const dim3 gconv((int)(Mc / 128), 8);
  const dim3 gp3((int)(PC * 256 / 128), 8);

  for (int ch = 0; ch < NCH; ++ch) {
    const int pbase = ch * PC;
    if (useXT) {
      k_mg<2, true><<<gconv, 256, 0, stream>>>(xtg, wpl, cb, h1, ssc, ssh, pbase, part);
    } else {
      k_gather<<<(int)(Mc / 16), 256, 0, stream>>>(x, ssc, ssh, xtg, pbase);
      k_mg<0, true><<<gconv, 256, 0, stream>>>(xtg, wpl, cb, h1, ssc, ssh, pbase, part);
    }
    k_statsfin<<<dim3(PC, 4), 256, 0, stream>>>(part, bng + CC, bnb + CC, ssc, ssh, pbase);
    k_mg<1, true><<<gconv, 256, 0, stream>>>(h1, wpl + 1ull * 1048576, cb + CC,
                                             h2, ssc, ssh, pbase, part);
    k_statsfin<<<dim3(PC, 4), 256, 0, stream>>>(part, bng + 2 * CC, bnb + 2 * CC, ssc, ssh, pbase);
    k_pool<<<PC * 256, 256, 0, stream>>>(h2, ssc, ssh, pooled, pbase);
    k_mg<0, false><<<gp3, 256, 0, stream>>>(pooled, wpl + 2ull * 1048576, cb + 2 * CC,
                                            ctx + (size_t)pbase * 256 * CC,
                                            nullptr, nullptr, 0, nullptr);
  }

  if (useCP) {
    k_wsplit<<<(6400 * 1024) / 256, 256, 0, stream>>>(ctx, ctxp, 6400 * 1024);
    k_heads<3><<<dim3(16, 120), 256, 0, stream>>>(ctx, ctxp, wpl + 3ull * 1048576, lb, out);
  } else {
    k_heads<0><<<dim3(16, 120), 256, 0, stream>>>(ctx, nullptr, wpl + 3ull * 1048576, lb, out);
  }
}